// Round 3
// baseline (665.585 us; speedup 1.0000x reference)
//
#include <hip/hip_runtime.h>
#include <hip/hip_fp16.h>

typedef unsigned short u16;
typedef unsigned int u32;
typedef __attribute__((ext_vector_type(8))) _Float16 f16x8;
typedef __attribute__((ext_vector_type(4))) float f32x4;

static __device__ __forceinline__ u16 f2h(float f) {
    __half h = __float2half(f);
    return __half_as_ushort(h);
}

// ---------------- RoPE tables: cos/sin[s][i], s<2048, i<64 ----------------
__global__ __launch_bounds__(256) void k_rope_tables(float* __restrict__ ct, float* __restrict__ st) {
    int idx = blockIdx.x * 256 + threadIdx.x;   // 2048*64 total
    int s = idx >> 6, i = idx & 63;
    float inv = 1.0f / powf(10000.0f, (float)i * (1.0f / 64.0f));
    float f = (float)s * inv;
    ct[idx] = cosf(f);
    st[idx] = sinf(f);
}

// ---------------- per-row absmax int8 quant (stored as exact-int f16) ----------------
__global__ __launch_bounds__(256) void k_quant_rows(const float* __restrict__ src,
        u16* __restrict__ dst, float* __restrict__ scales) {
    int row = blockIdx.x;
    const float* p = src + (size_t)row * 2048;
    int t = threadIdx.x;
    float4 v0 = ((const float4*)p)[t * 2 + 0];
    float4 v1 = ((const float4*)p)[t * 2 + 1];
    float amax = fmaxf(
        fmaxf(fmaxf(fabsf(v0.x), fabsf(v0.y)), fmaxf(fabsf(v0.z), fabsf(v0.w))),
        fmaxf(fmaxf(fabsf(v1.x), fabsf(v1.y)), fmaxf(fabsf(v1.z), fabsf(v1.w))));
#pragma unroll
    for (int d = 1; d < 64; d <<= 1) amax = fmaxf(amax, __shfl_xor(amax, d, 64));
    __shared__ float red[4];
    if ((t & 63) == 0) red[t >> 6] = amax;
    __syncthreads();
    amax = fmaxf(fmaxf(red[0], red[1]), fmaxf(red[2], red[3]));
    float scl = fmaxf(amax * (1.0f / 127.0f), 1e-5f);
    if (t == 0) scales[row] = scl;
    float vv[8] = {v0.x, v0.y, v0.z, v0.w, v1.x, v1.y, v1.z, v1.w};
    u16 q[8];
#pragma unroll
    for (int j = 0; j < 8; ++j) {
        float r = rintf(vv[j] / scl);           // RNE, matches jnp.round
        r = fminf(fmaxf(r, -127.0f), 127.0f);
        q[j] = f2h(r);                          // exact: |int| <= 127
    }
    *(uint4*)&dst[(size_t)row * 2048 + t * 8] = *(uint4*)q;
}

// ---------------- quantized GEMM: out[m][n] = (A[m,:].B[n,:]) * as[m]*ws[n] ----------------
#define BM 128
#define BN 128
#define BK 64
#define LDSP 72

__global__ __launch_bounds__(256) void k_gemm_q(const u16* __restrict__ A,
        const u16* __restrict__ B, const float* __restrict__ ascale,
        const float* __restrict__ wscale, float* __restrict__ out,
        int M, int N, int K) {
    __shared__ u16 As[BM][LDSP];
    __shared__ u16 Bs[BN][LDSP];
    int t = threadIdx.x;
    int wid = t >> 6, lane = t & 63;
    int bm = blockIdx.y * BM, bn = blockIdx.x * BN;
    int wm = (wid >> 1) * 64, wn = (wid & 1) * 64;
    int rl = lane & 15, kg = lane >> 4;

    f32x4 z = {0.f, 0.f, 0.f, 0.f};
    f32x4 acc[4][4];
#pragma unroll
    for (int i = 0; i < 4; ++i)
#pragma unroll
        for (int j = 0; j < 4; ++j) acc[i][j] = z;

    int sr = t >> 3, sc = (t & 7) * 8;
    const u16* Ab = A + (size_t)(bm + sr) * K + sc;
    const u16* Bb = B + (size_t)(bn + sr) * K + sc;
    uint4 ra[4], rb[4];
#pragma unroll
    for (int p = 0; p < 4; ++p) {
        ra[p] = *(const uint4*)(Ab + (size_t)p * 32 * K);
        rb[p] = *(const uint4*)(Bb + (size_t)p * 32 * K);
    }
    int NT = K / BK;
    for (int kt = 0; kt < NT; ++kt) {
#pragma unroll
        for (int p = 0; p < 4; ++p) {
            *(uint4*)&As[sr + p * 32][sc] = ra[p];
            *(uint4*)&Bs[sr + p * 32][sc] = rb[p];
        }
        __syncthreads();
        if (kt + 1 < NT) {
            size_t koff = (size_t)(kt + 1) * BK;
#pragma unroll
            for (int p = 0; p < 4; ++p) {
                ra[p] = *(const uint4*)(Ab + (size_t)p * 32 * K + koff);
                rb[p] = *(const uint4*)(Bb + (size_t)p * 32 * K + koff);
            }
        }
#pragma unroll
        for (int ks = 0; ks < 2; ++ks) {
            f16x8 af[4], bfr[4];
#pragma unroll
            for (int i = 0; i < 4; ++i)
                af[i] = *(const f16x8*)&As[wm + i * 16 + rl][ks * 32 + kg * 8];
#pragma unroll
            for (int j = 0; j < 4; ++j)
                bfr[j] = *(const f16x8*)&Bs[wn + j * 16 + rl][ks * 32 + kg * 8];
#pragma unroll
            for (int i = 0; i < 4; ++i)
#pragma unroll
                for (int j = 0; j < 4; ++j)
                    acc[i][j] = __builtin_amdgcn_mfma_f32_16x16x32_f16(af[i], bfr[j], acc[i][j], 0, 0, 0);
        }
        __syncthreads();
    }
#pragma unroll
    for (int i = 0; i < 4; ++i) {
#pragma unroll
        for (int j = 0; j < 4; ++j) {
            int n = bn + wn + j * 16 + rl;
            float wsn = wscale[n];
#pragma unroll
            for (int r = 0; r < 4; ++r) {
                int m = bm + wm + i * 16 + kg * 4 + r;
                out[(size_t)m * N + n] = acc[i][j][r] * ascale[m] * wsn;
            }
        }
    }
}

// ---------------- fused RMSNorm + RoPE + gain, split to q/k/v f16 buffers ----------------
__global__ __launch_bounds__(256) void k_rmsrope(const float* __restrict__ qkv,
        const float* __restrict__ qgain, const float* __restrict__ ct,
        const float* __restrict__ st, u16* __restrict__ qb,
        u16* __restrict__ kb, u16* __restrict__ vb) {
    int wave = blockIdx.x * 4 + (threadIdx.x >> 6);
    int lane = threadIdx.x & 63;
    int token = wave / 24, unit = wave - token * 24;
    int b = token >> 11, s = token & 2047;
    int col;
    if (unit < 16) col = unit * 128;
    else if (unit < 20) col = 2048 + (unit - 16) * 128;
    else col = 2560 + (unit - 20) * 128;
    const float* p = qkv + (size_t)token * 3072 + col;
    float x1 = p[lane], x2 = p[lane + 64];
    if (unit < 20) {
        float ss = x1 * x1 + x2 * x2;
#pragma unroll
        for (int d = 1; d < 64; d <<= 1) ss += __shfl_xor(ss, d, 64);
        float rn = rsqrtf(ss * (1.0f / 128.0f) + 1.1920929e-07f);
        x1 *= rn; x2 *= rn;
        float c = ct[s * 64 + lane], sn = st[s * 64 + lane];
        float o1 = x1 * c + x2 * sn;
        float o2 = x2 * c - x1 * sn;
        if (unit < 16) {
            float g = qgain[unit] * 0.08838834764831845f;  // fold 1/sqrt(128) into q
            o1 *= g; o2 *= g;
        }
        x1 = o1; x2 = o2;
    }
    u16 u1 = f2h(x1), u2 = f2h(x2);
    size_t off; u16* dst;
    if (unit < 16)      { dst = qb; off = ((size_t)(b * 16 + unit) * 2048 + s) * 128; }
    else if (unit < 20) { dst = kb; off = ((size_t)(b * 4 + (unit - 16)) * 2048 + s) * 128; }
    else                { dst = vb; off = ((size_t)(b * 4 + (unit - 20)) * 2048 + s) * 128; }
    dst[off + lane] = u1;
    dst[off + lane + 64] = u2;
}

// ---------------- V transpose: [bh][s][128] -> [bh][d][2048] ----------------
__global__ __launch_bounds__(256) void k_transpose_v(const u16* __restrict__ vb,
        u16* __restrict__ vt) {
    __shared__ u16 tls[64][72];
    int bh = blockIdx.x;
    int s0 = blockIdx.y * 64;
    int d0 = blockIdx.z * 64;
    const u16* src = vb + (size_t)bh * 2048 * 128;
    u16* dst = vt + (size_t)bh * 128 * 2048;
    int r = threadIdx.x >> 3, c = (threadIdx.x & 7) * 8;
#pragma unroll
    for (int p = 0; p < 2; ++p) {
        uint4 d4 = *(const uint4*)&src[(size_t)(s0 + r + p * 32) * 128 + d0 + c];
        u16 tmp[8]; *(uint4*)tmp = d4;
#pragma unroll
        for (int j = 0; j < 8; ++j) tls[c + j][r + p * 32] = tmp[j];
    }
    __syncthreads();
#pragma unroll
    for (int p = 0; p < 2; ++p) {
        int dd = r + p * 32;
        u16 tmp[8];
#pragma unroll
        for (int j = 0; j < 8; ++j) tmp[j] = tls[dd][c + j];
        *(uint4*)&dst[(size_t)(d0 + dd) * 2048 + s0 + c] = *(uint4*)tmp;
    }
}

// ---------------- flash attention: causal GQA, swapped-operand, kv-split x4 ----------------
// Grid: (64 pairs, 16 heads, 2 batch). Block = 16 q rows (qc = pair, then 127-pair).
// 4 waves split the kv tiles round-robin (own m,l,o), merged via LDS at phase end.
// Swapped QK^T: P[kv][q] with q lane-local -> softmax reduce = in-reg + 2 shuffles.
// PV as o^T = mfma(V^T, P^T): alpha and 1/l lane-local; float4 output stores.
__global__ __launch_bounds__(256, 3) void k_attn(const u16* __restrict__ qb,
        const u16* __restrict__ kb, const u16* __restrict__ vt,
        float* __restrict__ y) {
    int pr = blockIdx.x, h = blockIdx.y, b = blockIdx.z;
    int wid = threadIdx.x >> 6, lane = threadIdx.x & 63;
    int kvh = h >> 2;
    int rl = lane & 15, kg = lane >> 4;
    const u16* kp = kb + (size_t)(b * 4 + kvh) * 2048 * 128;
    const u16* vp = vt + (size_t)(b * 4 + kvh) * 128 * 2048;

    __shared__ __align__(16) u16 Ps[4][16][56];   // stride 112B: 16B-aligned rows, 2-way banks
    __shared__ float om[4][16][132];              // per-wave o^T partials (row pad: 2-way banks)
    __shared__ float mlm[4][2][16];               // per-wave m,l per q-row
    f32x4 z = {0.f, 0.f, 0.f, 0.f};

    for (int phase = 0; phase < 2; ++phase) {
        int qc = phase ? (127 - pr) : pr;
        int q0 = qc * 16;
        const u16* qp = qb + ((size_t)(b * 16 + h) * 2048 + q0) * 128;

        f16x8 qf[4];
#pragma unroll
        for (int kc = 0; kc < 4; ++kc)
            qf[kc] = *(const f16x8*)&qp[(size_t)rl * 128 + kc * 32 + kg * 8];

        f32x4 o[8];
#pragma unroll
        for (int j = 0; j < 8; ++j) o[j] = z;
        float m = -3.0e38f, l = 0.f;
        int qrow = q0 + rl;
        int nsteps = (q0 + 47) >> 5;   // kv tiles of 32 covering cols <= q0+15

        for (int t = wid; t < nsteps; t += 4) {
            int kv0 = t * 32;
            // K loads (A-frag: rows=kv), then V loads (A-frag: rows=d) -> QK waits only on K
            f16x8 kf[2][4];
#pragma unroll
            for (int nt = 0; nt < 2; ++nt)
#pragma unroll
                for (int kc = 0; kc < 4; ++kc)
                    kf[nt][kc] = *(const f16x8*)&kp[(size_t)(kv0 + nt * 16 + rl) * 128 + kc * 32 + kg * 8];
            f16x8 vf[8];
#pragma unroll
            for (int j = 0; j < 8; ++j)
                vf[j] = *(const f16x8*)&vp[(size_t)(j * 16 + rl) * 2048 + kv0 + kg * 8];
            // QK^T swapped: sc[nt] rows = kv (kg*4+r), col = q (rl)
            f32x4 sc[2];
#pragma unroll
            for (int nt = 0; nt < 2; ++nt) {
                f32x4 acc = z;
#pragma unroll
                for (int kc = 0; kc < 4; ++kc)
                    acc = __builtin_amdgcn_mfma_f32_16x16x32_f16(kf[nt][kc], qf[kc], acc, 0, 0, 0);
                sc[nt] = acc;
            }
            // causal mask: kv = kv0 + nt*16 + kg*4 + r > qrow
            int thr = qrow - kv0 - kg * 4;
#pragma unroll
            for (int nt = 0; nt < 2; ++nt)
#pragma unroll
                for (int r = 0; r < 4; ++r)
                    if (nt * 16 + r > thr) sc[nt][r] = -3.0e38f;
            // online softmax: in-register over 8 vals + 2 shuffles over kg groups
            float pm = fmaxf(
                fmaxf(fmaxf(sc[0][0], sc[0][1]), fmaxf(sc[0][2], sc[0][3])),
                fmaxf(fmaxf(sc[1][0], sc[1][1]), fmaxf(sc[1][2], sc[1][3])));
            pm = fmaxf(pm, __shfl_xor(pm, 16, 64));
            pm = fmaxf(pm, __shfl_xor(pm, 32, 64));
            float mnew = fmaxf(m, pm);
            float alpha = __expf(m - mnew);
            float p[8];
#pragma unroll
            for (int nt = 0; nt < 2; ++nt)
#pragma unroll
                for (int r = 0; r < 4; ++r)
                    p[nt * 4 + r] = __expf(sc[nt][r] - mnew);
            float rs = ((p[0] + p[1]) + (p[2] + p[3])) + ((p[4] + p[5]) + (p[6] + p[7]));
            rs += __shfl_xor(rs, 16, 64);
            rs += __shfl_xor(rs, 32, 64);
            l = l * alpha + rs;
            m = mnew;
            // rescale o (alpha lane-local scalar)
#pragma unroll
            for (int j = 0; j < 8; ++j) o[j] *= alpha;
            // P bounce: write P[q=rl][kv], read back P^T B-frag
#pragma unroll
            for (int nt = 0; nt < 2; ++nt) {
                u32 pk0 = (u32)f2h(p[nt * 4 + 0]) | ((u32)f2h(p[nt * 4 + 1]) << 16);
                u32 pk1 = (u32)f2h(p[nt * 4 + 2]) | ((u32)f2h(p[nt * 4 + 3]) << 16);
                *(u32*)&Ps[wid][rl][nt * 16 + kg * 4]     = pk0;
                *(u32*)&Ps[wid][rl][nt * 16 + kg * 4 + 2] = pk1;
            }
            f16x8 pB = *(const f16x8*)&Ps[wid][rl][kg * 8];
            // PV: o^T[d][q] += V^T . P^T
#pragma unroll
            for (int j = 0; j < 8; ++j)
                o[j] = __builtin_amdgcn_mfma_f32_16x16x32_f16(vf[j], pB, o[j], 0, 0, 0);
        }
        // publish partials
        if (kg == 0) { mlm[wid][0][rl] = m; mlm[wid][1][rl] = l; }
#pragma unroll
        for (int j = 0; j < 8; ++j)
            *(f32x4*)&om[wid][rl][j * 16 + kg * 4] = o[j];
        __syncthreads();
        // merge: this thread handles q=rl, d in [wid*32 + kg*8, +8)
        float mw[4], lw[4];
#pragma unroll
        for (int w = 0; w < 4; ++w) { mw[w] = mlm[w][0][rl]; lw[w] = mlm[w][1][rl]; }
        float M = fmaxf(fmaxf(mw[0], mw[1]), fmaxf(mw[2], mw[3]));
        float aw[4], lsum = 0.f;
#pragma unroll
        for (int w = 0; w < 4; ++w) { aw[w] = __expf(mw[w] - M); lsum += aw[w] * lw[w]; }
        float linv = 1.0f / lsum;
        int d0 = wid * 32 + kg * 8;
#pragma unroll
        for (int seg = 0; seg < 2; ++seg) {
            f32x4 acc = z;
#pragma unroll
            for (int w = 0; w < 4; ++w) {
                f32x4 v = *(const f32x4*)&om[w][rl][d0 + seg * 4];
                acc += aw[w] * v;
            }
            acc *= linv;
            *(f32x4*)&y[(size_t)(b * 2048 + q0 + rl) * 2048 + h * 128 + d0 + seg * 4] = acc;
        }
        __syncthreads();
    }
}

extern "C" void kernel_launch(void* const* d_in, const int* in_sizes, int n_in,
                              void* d_out, int out_size, void* d_ws, size_t ws_size,
                              hipStream_t stream) {
    const float* x     = (const float*)d_in[0];
    const float* w_q   = (const float*)d_in[1];
    const float* w_k   = (const float*)d_in[2];
    const float* w_v   = (const float*)d_in[3];
    const float* w_o   = (const float*)d_in[4];
    const float* qgain = (const float*)d_in[5];
    float* out = (float*)d_out;

    char* ws = (char*)d_ws;
    size_t off = 0;
    auto alloc = [&](size_t bytes) {
        char* p = ws + off;
        off += (bytes + 255) & ~(size_t)255;
        return (void*)p;
    };
    u16*   wqf  = (u16*)  alloc(3072ull * 2048 * 2);
    u16*   wqo  = (u16*)  alloc(2048ull * 2048 * 2);
    float* wsc  = (float*)alloc(5120 * 4);
    float* asc  = (float*)alloc(4096 * 4);
    float* ysc  = (float*)alloc(4096 * 4);
    float* ctab = (float*)alloc(2048ull * 64 * 4);
    float* stab = (float*)alloc(2048ull * 64 * 4);
    u16*   xq   = (u16*)  alloc(4096ull * 2048 * 2);
    float* qkv  = (float*)alloc(4096ull * 3072 * 4);
    u16*   qbuf = (u16*)  alloc(2ull * 16 * 2048 * 128 * 2);
    u16*   kbuf = (u16*)  alloc(2ull * 4 * 2048 * 128 * 2);
    u16*   vbuf = (u16*)  alloc(2ull * 4 * 2048 * 128 * 2);
    u16*   vtb  = (u16*)  alloc(2ull * 4 * 128 * 2048 * 2);
    (void)ws_size; (void)in_sizes; (void)n_in; (void)out_size;

    k_rope_tables<<<512, 256, 0, stream>>>(ctab, stab);
    k_quant_rows<<<2048, 256, 0, stream>>>(w_q, wqf, wsc);
    k_quant_rows<<<512, 256, 0, stream>>>(w_k, wqf + 2048ull * 2048, wsc + 2048);
    k_quant_rows<<<512, 256, 0, stream>>>(w_v, wqf + 2560ull * 2048, wsc + 2560);
    k_quant_rows<<<2048, 256, 0, stream>>>(w_o, wqo, wsc + 3072);
    k_quant_rows<<<4096, 256, 0, stream>>>(x, xq, asc);

    k_gemm_q<<<dim3(3072 / BN, 4096 / BM), 256, 0, stream>>>(xq, wqf, asc, wsc, qkv, 4096, 3072, 2048);
    k_rmsrope<<<(4096 * 24) / 4, 256, 0, stream>>>(qkv, qgain, ctab, stab, qbuf, kbuf, vbuf);
    k_transpose_v<<<dim3(8, 32, 2), 256, 0, stream>>>(vbuf, vtb);

    float* ybuf = qkv;
    k_attn<<<dim3(64, 16, 2), 256, 0, stream>>>(qbuf, kbuf, vtb, ybuf);

    u16* yq = xq;
    k_quant_rows<<<4096, 256, 0, stream>>>(ybuf, yq, ysc);
    k_gemm_q<<<dim3(2048 / BN, 4096 / BM), 256, 0, stream>>>(yq, wqo, ysc, wsc + 3072, out, 4096, 2048, 2048);
}

// Round 5
// 569.754 us; speedup vs baseline: 1.1682x; 1.1682x over previous
//
#include <hip/hip_runtime.h>
#include <hip/hip_fp16.h>

typedef unsigned short u16;
typedef unsigned int u32;
typedef __attribute__((ext_vector_type(8))) _Float16 f16x8;
typedef __attribute__((ext_vector_type(4))) float f32x4;
typedef __attribute__((ext_vector_type(16))) float f32x16;

static __device__ __forceinline__ u16 f2h(float f) {
    __half h = __float2half(f);
    return __half_as_ushort(h);
}

// ---------------- RoPE tables: cos/sin[s][i], s<2048, i<64 ----------------
__global__ __launch_bounds__(256) void k_rope_tables(float* __restrict__ ct, float* __restrict__ st) {
    int idx = blockIdx.x * 256 + threadIdx.x;   // 2048*64 total
    int s = idx >> 6, i = idx & 63;
    float inv = 1.0f / powf(10000.0f, (float)i * (1.0f / 64.0f));
    float f = (float)s * inv;
    ct[idx] = cosf(f);
    st[idx] = sinf(f);
}

// ---------------- per-row absmax int8 quant (stored as exact-int f16) ----------------
__global__ __launch_bounds__(256) void k_quant_rows(const float* __restrict__ src,
        u16* __restrict__ dst, float* __restrict__ scales) {
    int row = blockIdx.x;
    const float* p = src + (size_t)row * 2048;
    int t = threadIdx.x;
    float4 v0 = ((const float4*)p)[t * 2 + 0];
    float4 v1 = ((const float4*)p)[t * 2 + 1];
    float amax = fmaxf(
        fmaxf(fmaxf(fabsf(v0.x), fabsf(v0.y)), fmaxf(fabsf(v0.z), fabsf(v0.w))),
        fmaxf(fmaxf(fabsf(v1.x), fabsf(v1.y)), fmaxf(fabsf(v1.z), fabsf(v1.w))));
#pragma unroll
    for (int d = 1; d < 64; d <<= 1) amax = fmaxf(amax, __shfl_xor(amax, d, 64));
    __shared__ float red[4];
    if ((t & 63) == 0) red[t >> 6] = amax;
    __syncthreads();
    amax = fmaxf(fmaxf(red[0], red[1]), fmaxf(red[2], red[3]));
    float scl = fmaxf(amax * (1.0f / 127.0f), 1e-5f);
    if (t == 0) scales[row] = scl;
    float vv[8] = {v0.x, v0.y, v0.z, v0.w, v1.x, v1.y, v1.z, v1.w};
    u16 q[8];
#pragma unroll
    for (int j = 0; j < 8; ++j) {
        float r = rintf(vv[j] / scl);           // RNE, matches jnp.round
        r = fminf(fmaxf(r, -127.0f), 127.0f);
        q[j] = f2h(r);                          // exact: |int| <= 127
    }
    *(uint4*)&dst[(size_t)row * 2048 + t * 8] = *(uint4*)q;
}

// ---------------- quantized GEMM: out[m][n] = (A[m,:].B[n,:]) * as[m]*ws[n] ----------------
#define BM 128
#define BN 128
#define BK 64
#define LDSP 72

__global__ __launch_bounds__(256) void k_gemm_q(const u16* __restrict__ A,
        const u16* __restrict__ B, const float* __restrict__ ascale,
        const float* __restrict__ wscale, float* __restrict__ out,
        int M, int N, int K) {
    __shared__ u16 As[BM][LDSP];
    __shared__ u16 Bs[BN][LDSP];
    int t = threadIdx.x;
    int wid = t >> 6, lane = t & 63;
    int bm = blockIdx.y * BM, bn = blockIdx.x * BN;
    int wm = (wid >> 1) * 64, wn = (wid & 1) * 64;
    int rl = lane & 15, kg = lane >> 4;

    f32x4 z = {0.f, 0.f, 0.f, 0.f};
    f32x4 acc[4][4];
#pragma unroll
    for (int i = 0; i < 4; ++i)
#pragma unroll
        for (int j = 0; j < 4; ++j) acc[i][j] = z;

    int sr = t >> 3, sc = (t & 7) * 8;
    const u16* Ab = A + (size_t)(bm + sr) * K + sc;
    const u16* Bb = B + (size_t)(bn + sr) * K + sc;
    uint4 ra[4], rb[4];
#pragma unroll
    for (int p = 0; p < 4; ++p) {
        ra[p] = *(const uint4*)(Ab + (size_t)p * 32 * K);
        rb[p] = *(const uint4*)(Bb + (size_t)p * 32 * K);
    }
    int NT = K / BK;
    for (int kt = 0; kt < NT; ++kt) {
#pragma unroll
        for (int p = 0; p < 4; ++p) {
            *(uint4*)&As[sr + p * 32][sc] = ra[p];
            *(uint4*)&Bs[sr + p * 32][sc] = rb[p];
        }
        __syncthreads();
        if (kt + 1 < NT) {
            size_t koff = (size_t)(kt + 1) * BK;
#pragma unroll
            for (int p = 0; p < 4; ++p) {
                ra[p] = *(const uint4*)(Ab + (size_t)p * 32 * K + koff);
                rb[p] = *(const uint4*)(Bb + (size_t)p * 32 * K + koff);
            }
        }
#pragma unroll
        for (int ks = 0; ks < 2; ++ks) {
            f16x8 af[4], bfr[4];
#pragma unroll
            for (int i = 0; i < 4; ++i)
                af[i] = *(const f16x8*)&As[wm + i * 16 + rl][ks * 32 + kg * 8];
#pragma unroll
            for (int j = 0; j < 4; ++j)
                bfr[j] = *(const f16x8*)&Bs[wn + j * 16 + rl][ks * 32 + kg * 8];
#pragma unroll
            for (int i = 0; i < 4; ++i)
#pragma unroll
                for (int j = 0; j < 4; ++j)
                    acc[i][j] = __builtin_amdgcn_mfma_f32_16x16x32_f16(af[i], bfr[j], acc[i][j], 0, 0, 0);
        }
        __syncthreads();
    }
#pragma unroll
    for (int i = 0; i < 4; ++i) {
#pragma unroll
        for (int j = 0; j < 4; ++j) {
            int n = bn + wn + j * 16 + rl;
            float wsn = wscale[n];
#pragma unroll
            for (int r = 0; r < 4; ++r) {
                int m = bm + wm + i * 16 + kg * 4 + r;
                out[(size_t)m * N + n] = acc[i][j][r] * ascale[m] * wsn;
            }
        }
    }
}

// ---------------- fused RMSNorm + RoPE + gain, split to q/k/v f16 buffers ----------------
__global__ __launch_bounds__(256) void k_rmsrope(const float* __restrict__ qkv,
        const float* __restrict__ qgain, const float* __restrict__ ct,
        const float* __restrict__ st, u16* __restrict__ qb,
        u16* __restrict__ kb, u16* __restrict__ vb) {
    int wave = blockIdx.x * 4 + (threadIdx.x >> 6);
    int lane = threadIdx.x & 63;
    int token = wave / 24, unit = wave - token * 24;
    int b = token >> 11, s = token & 2047;
    int col;
    if (unit < 16) col = unit * 128;
    else if (unit < 20) col = 2048 + (unit - 16) * 128;
    else col = 2560 + (unit - 20) * 128;
    const float* p = qkv + (size_t)token * 3072 + col;
    float x1 = p[lane], x2 = p[lane + 64];
    if (unit < 20) {
        float ss = x1 * x1 + x2 * x2;
#pragma unroll
        for (int d = 1; d < 64; d <<= 1) ss += __shfl_xor(ss, d, 64);
        float rn = rsqrtf(ss * (1.0f / 128.0f) + 1.1920929e-07f);
        x1 *= rn; x2 *= rn;
        float c = ct[s * 64 + lane], sn = st[s * 64 + lane];
        float o1 = x1 * c + x2 * sn;
        float o2 = x2 * c - x1 * sn;
        if (unit < 16) {
            float g = qgain[unit] * 0.08838834764831845f;  // fold 1/sqrt(128) into q
            o1 *= g; o2 *= g;
        }
        x1 = o1; x2 = o2;
    }
    u16 u1 = f2h(x1), u2 = f2h(x2);
    size_t off; u16* dst;
    if (unit < 16)      { dst = qb; off = ((size_t)(b * 16 + unit) * 2048 + s) * 128; }
    else if (unit < 20) { dst = kb; off = ((size_t)(b * 4 + (unit - 16)) * 2048 + s) * 128; }
    else                { dst = vb; off = ((size_t)(b * 4 + (unit - 20)) * 2048 + s) * 128; }
    dst[off + lane] = u1;
    dst[off + lane + 64] = u2;
}

// ---------------- V transpose: [bh][s][128] -> [bh][d][2048] ----------------
__global__ __launch_bounds__(256) void k_transpose_v(const u16* __restrict__ vb,
        u16* __restrict__ vt) {
    __shared__ u16 tls[64][72];
    int bh = blockIdx.x;
    int s0 = blockIdx.y * 64;
    int d0 = blockIdx.z * 64;
    const u16* src = vb + (size_t)bh * 2048 * 128;
    u16* dst = vt + (size_t)bh * 128 * 2048;
    int r = threadIdx.x >> 3, c = (threadIdx.x & 7) * 8;
#pragma unroll
    for (int p = 0; p < 2; ++p) {
        uint4 d4 = *(const uint4*)&src[(size_t)(s0 + r + p * 32) * 128 + d0 + c];
        u16 tmp[8]; *(uint4*)tmp = d4;
#pragma unroll
        for (int j = 0; j < 8; ++j) tls[c + j][r + p * 32] = tmp[j];
    }
    __syncthreads();
#pragma unroll
    for (int p = 0; p < 2; ++p) {
        int dd = r + p * 32;
        u16 tmp[8];
#pragma unroll
        for (int j = 0; j < 8; ++j) tmp[j] = tls[dd][c + j];
        *(uint4*)&dst[(size_t)(d0 + dd) * 2048 + s0 + c] = *(uint4*)tmp;
    }
}

// ---------------- flash attention v3: LDS-shared KV, 128q block, 32x32 MFMA ----------------
// Grid (8 pairs, 16 h, 2 b) = 256 blocks, 1/CU. Block: 128 q rows (qb = pr, then 15-pr),
// 4 waves x 32 rows. KV tiles of 64 staged once per block into padded LDS (double-buffered,
// reg-staged T14 split), consumed by all 4 waves. Swapped QK (q lane-local), PV transposed.
// LDS (dynamic 90112B): K[2][64][136]u16 | V[2][128][72]u16 | P[4][32][72]u16
#define KLDS_OFF 0
#define VLDS_OFF 34816
#define PLDS_OFF 71680
__global__ __launch_bounds__(256, 1) void k_attn(const u16* __restrict__ qbuf,
        const u16* __restrict__ kbuf, const u16* __restrict__ vt,
        float* __restrict__ y) {
    extern __shared__ char smem[];
    u16* Klds = (u16*)(smem + KLDS_OFF);
    u16* Vlds = (u16*)(smem + VLDS_OFF);
    u16* Plds = (u16*)(smem + PLDS_OFF);

    int pr = blockIdx.x, h = blockIdx.y, b = blockIdx.z;
    int tid = threadIdx.x;
    int wid = tid >> 6, lane = tid & 63;
    int rl32 = lane & 31, hi = lane >> 5;
    int kvh = h >> 2;
    const u16* kp = kbuf + (size_t)(b * 4 + kvh) * 2048 * 128;
    const u16* vp = vt + (size_t)(b * 4 + kvh) * 128 * 2048;

    // staging map: K: 4 passes, row=p*16+(tid>>4), ch=tid&15 (16B units)
    //              V: 4 passes, d=p*32+(tid>>3), ch=tid&7
    int k_row = tid >> 4, k_ch = tid & 15;
    int v_d = tid >> 3, v_ch = tid & 7;
    u16* pw = Plds + wid * (32 * 72) + rl32 * 72;   // this lane's P row (q = rl32)

    for (int phase = 0; phase < 2; ++phase) {
        int qb = phase ? (15 - pr) : pr;
        int q0 = qb * 128;
        int wq0 = q0 + wid * 32;
        int nsteps = 2 * qb + 2;
        int nw = (wq0 + 95) >> 6;   // tiles this wave computes

        // Q fragments (B-operand: col q = lane&31, k-chunk by hi)
        const u16* qp = qbuf + ((size_t)(b * 16 + h) * 2048 + q0 + wid * 32 + rl32) * 128;
        f16x8 qf[8];
#pragma unroll
        for (int kc = 0; kc < 8; ++kc)
            qf[kc] = *(const f16x8*)(qp + kc * 16 + hi * 8);

        f32x16 o_[4];
#pragma unroll
        for (int j = 0; j < 4; ++j)
#pragma unroll
            for (int r = 0; r < 16; ++r) o_[j][r] = 0.f;
        float m = -3.0e38f, l = 0.f;

        uint4 rk[4], rv[4];
        // prologue: stage tile 0
#pragma unroll
        for (int p = 0; p < 4; ++p) {
            rk[p] = *(const uint4*)(kp + (size_t)(p * 16 + k_row) * 128 + k_ch * 8);
            rv[p] = *(const uint4*)(vp + (size_t)(p * 32 + v_d) * 2048 + v_ch * 8);
        }
#pragma unroll
        for (int p = 0; p < 4; ++p) {
            *(uint4*)(Klds + (p * 16 + k_row) * 136 + k_ch * 8) = rk[p];
            *(uint4*)(Vlds + (p * 32 + v_d) * 72 + v_ch * 8) = rv[p];
        }
        __syncthreads();

        for (int t = 0; t < nsteps; ++t) {
            int sel = t & 1;
            bool pre = (t + 1 < nsteps);
            if (pre) {
                int kn0 = (t + 1) * 64;
#pragma unroll
                for (int p = 0; p < 4; ++p) {
                    rk[p] = *(const uint4*)(kp + (size_t)(kn0 + p * 16 + k_row) * 128 + k_ch * 8);
                    rv[p] = *(const uint4*)(vp + (size_t)(p * 32 + v_d) * 2048 + kn0 + v_ch * 8);
                }
            }
            if (t < nw) {
                int kv0 = t * 64;
                const u16* kb_ = Klds + sel * (64 * 136);
                const u16* vb_ = Vlds + sel * (128 * 72);
                // QK^T swapped: s0 = K[0:32] x Q, s1 = K[32:64] x Q
                f32x16 s0, s1;
#pragma unroll
                for (int r = 0; r < 16; ++r) { s0[r] = 0.f; s1[r] = 0.f; }
#pragma unroll
                for (int kc = 0; kc < 8; ++kc) {
                    f16x8 kf0 = *(const f16x8*)(kb_ + (size_t)rl32 * 136 + (kc * 2 + hi) * 8);
                    s0 = __builtin_amdgcn_mfma_f32_32x32x16_f16(kf0, qf[kc], s0, 0, 0, 0);
                }
#pragma unroll
                for (int kc = 0; kc < 8; ++kc) {
                    f16x8 kf1 = *(const f16x8*)(kb_ + (size_t)(32 + rl32) * 136 + (kc * 2 + hi) * 8);
                    s1 = __builtin_amdgcn_mfma_f32_32x32x16_f16(kf1, qf[kc], s1, 0, 0, 0);
                }
                // causal mask (only diagonal-ish tiles): kv = kv0 + nt*32 + (r&3)+8*(r>>2)+4*hi
                if (kv0 + 63 > wq0) {
                    int rel = (wq0 + rl32) - kv0 - 4 * hi;
#pragma unroll
                    for (int r = 0; r < 16; ++r) {
                        int kb0 = (r & 3) + 8 * (r >> 2);
                        if (kb0 > rel) s0[r] = -3.0e38f;
                        if (kb0 + 32 > rel) s1[r] = -3.0e38f;
                    }
                }
                // online softmax: in-reg over 32 + one shuffle over hi
                float pm = -3.0e38f;
#pragma unroll
                for (int r = 0; r < 16; ++r) pm = fmaxf(pm, fmaxf(s0[r], s1[r]));
                pm = fmaxf(pm, __shfl_xor(pm, 32, 64));
                float mnew = fmaxf(m, pm);
                float alpha = __expf(m - mnew);
                m = mnew;
                float a0 = 0.f, a1 = 0.f;
#pragma unroll
                for (int r = 0; r < 16; ++r) {
                    s0[r] = __expf(s0[r] - mnew);
                    s1[r] = __expf(s1[r] - mnew);
                    a0 += s0[r]; a1 += s1[r];
                }
                float rs = a0 + a1;
                rs += __shfl_xor(rs, 32, 64);
                l = l * alpha + rs;
#pragma unroll
                for (int j = 0; j < 4; ++j) o_[j] *= alpha;
                // P -> LDS (own row, kv-major packed 4-wide), then B-frags back
#pragma unroll
                for (int g = 0; g < 4; ++g) {
                    u16 q0w[4], q1w[4];
#pragma unroll
                    for (int e = 0; e < 4; ++e) {
                        q0w[e] = f2h(s0[4 * g + e]);
                        q1w[e] = f2h(s1[4 * g + e]);
                    }
                    *(uint2*)(pw + 8 * g + 4 * hi) = *(uint2*)q0w;
                    *(uint2*)(pw + 32 + 8 * g + 4 * hi) = *(uint2*)q1w;
                }
                f16x8 pf[4];
#pragma unroll
                for (int ks = 0; ks < 4; ++ks)
                    pf[ks] = *(const f16x8*)(pw + ks * 16 + hi * 8);
                // PV: o^T[d][q] += V^T x P^T
#pragma unroll
                for (int j = 0; j < 4; ++j)
#pragma unroll
                    for (int ks = 0; ks < 4; ++ks) {
                        f16x8 vf = *(const f16x8*)(vb_ + (size_t)(j * 32 + rl32) * 72 + (ks * 2 + hi) * 8);
                        o_[j] = __builtin_amdgcn_mfma_f32_32x32x16_f16(vf, pf[ks], o_[j], 0, 0, 0);
                    }
            }
            __syncthreads();   // B1: all waves done reading buf[sel]
            if (pre) {
                int nsel = (t + 1) & 1;
#pragma unroll
                for (int p = 0; p < 4; ++p) {
                    *(uint4*)(Klds + nsel * (64 * 136) + (p * 16 + k_row) * 136 + k_ch * 8) = rk[p];
                    *(uint4*)(Vlds + nsel * (128 * 72) + (p * 32 + v_d) * 72 + v_ch * 8) = rv[p];
                }
            }
            __syncthreads();   // B2: next buffer ready
        }

        // epilogue: o / l, direct f32x4 stores (d-consecutive regs)
        float linv = 1.0f / l;
        float* yrow = y + ((size_t)(b * 2048 + q0 + wid * 32 + rl32)) * 2048 + h * 128;
#pragma unroll
        for (int j = 0; j < 4; ++j)
#pragma unroll
            for (int g = 0; g < 4; ++g) {
                f32x4 v4 = { o_[j][4 * g + 0] * linv, o_[j][4 * g + 1] * linv,
                             o_[j][4 * g + 2] * linv, o_[j][4 * g + 3] * linv };
                *(f32x4*)(yrow + j * 32 + 8 * g + 4 * hi) = v4;
            }
    }
}

extern "C" void kernel_launch(void* const* d_in, const int* in_sizes, int n_in,
                              void* d_out, int out_size, void* d_ws, size_t ws_size,
                              hipStream_t stream) {
    const float* x     = (const float*)d_in[0];
    const float* w_q   = (const float*)d_in[1];
    const float* w_k   = (const float*)d_in[2];
    const float* w_v   = (const float*)d_in[3];
    const float* w_o   = (const float*)d_in[4];
    const float* qgain = (const float*)d_in[5];
    float* out = (float*)d_out;

    char* ws = (char*)d_ws;
    size_t off = 0;
    auto alloc = [&](size_t bytes) {
        char* p = ws + off;
        off += (bytes + 255) & ~(size_t)255;
        return (void*)p;
    };
    u16*   wqf  = (u16*)  alloc(3072ull * 2048 * 2);
    u16*   wqo  = (u16*)  alloc(2048ull * 2048 * 2);
    float* wsc  = (float*)alloc(5120 * 4);
    float* asc  = (float*)alloc(4096 * 4);
    float* ysc  = (float*)alloc(4096 * 4);
    float* ctab = (float*)alloc(2048ull * 64 * 4);
    float* stab = (float*)alloc(2048ull * 64 * 4);
    u16*   xq   = (u16*)  alloc(4096ull * 2048 * 2);
    float* qkv  = (float*)alloc(4096ull * 3072 * 4);
    u16*   qbuf = (u16*)  alloc(2ull * 16 * 2048 * 128 * 2);
    u16*   kbuf = (u16*)  alloc(2ull * 4 * 2048 * 128 * 2);
    u16*   vbuf = (u16*)  alloc(2ull * 4 * 2048 * 128 * 2);
    u16*   vtb  = (u16*)  alloc(2ull * 4 * 128 * 2048 * 2);
    (void)ws_size; (void)in_sizes; (void)n_in; (void)out_size;

    (void)hipFuncSetAttribute((const void*)k_attn,
                              hipFuncAttributeMaxDynamicSharedMemorySize, 90112);

    k_rope_tables<<<512, 256, 0, stream>>>(ctab, stab);
    k_quant_rows<<<2048, 256, 0, stream>>>(w_q, wqf, wsc);
    k_quant_rows<<<512, 256, 0, stream>>>(w_k, wqf + 2048ull * 2048, wsc + 2048);
    k_quant_rows<<<512, 256, 0, stream>>>(w_v, wqf + 2560ull * 2048, wsc + 2560);
    k_quant_rows<<<2048, 256, 0, stream>>>(w_o, wqo, wsc + 3072);
    k_quant_rows<<<4096, 256, 0, stream>>>(x, xq, asc);

    k_gemm_q<<<dim3(3072 / BN, 4096 / BM), 256, 0, stream>>>(xq, wqf, asc, wsc, qkv, 4096, 3072, 2048);
    k_rmsrope<<<(4096 * 24) / 4, 256, 0, stream>>>(qkv, qgain, ctab, stab, qbuf, kbuf, vbuf);
    k_transpose_v<<<dim3(8, 32, 2), 256, 0, stream>>>(vbuf, vtb);

    float* ybuf = qkv;
    k_attn<<<dim3(8, 16, 2), 256, 90112, stream>>>(qbuf, kbuf, vtb, ybuf);

    u16* yq = xq;
    k_quant_rows<<<4096, 256, 0, stream>>>(ybuf, yq, ysc);
    k_gemm_q<<<dim3(2048 / BN, 4096 / BM), 256, 0, stream>>>(yq, wqo, ysc, wsc + 3072, out, 4096, 2048, 2048);
}